// Round 6
// baseline (638.759 us; speedup 1.0000x reference)
//
#include <hip/hip_runtime.h>
#include <math.h>

// B=4, N=2048, H=8, CM=8, CS=16 ; head dim 144 padded to 160 (5 chunks of 32)
// qf/kf/vf: bf16 (b,h,n,160); ho: f32 (b,h,n,144) head-contiguous

typedef float f32x4 __attribute__((ext_vector_type(4)));
typedef __bf16 bf16x8 __attribute__((ext_vector_type(8)));
typedef unsigned short u16;
typedef unsigned int u32;

#define ATT_SCALE (1.0f/12.0f)

__device__ __forceinline__ u32 pack2(float a, float b) {
  u32 ua = __builtin_bit_cast(u32, a);
  u32 ub = __builtin_bit_cast(u32, b);
  ua = (ua + 0x7fffu + ((ua >> 16) & 1u)) >> 16;
  ub = (ub + 0x7fffu + ((ub >> 16) & 1u)) >> 16;
  return ua | (ub << 16);
}
__device__ __forceinline__ u16 bf16of(float a) { return (u16)(pack2(a, 0.f) & 0xffffu); }

__device__ __forceinline__ f32x4 mfma_bf16(uint4 a, uint4 b, f32x4 c) {
  return __builtin_amdgcn_mfma_f32_16x16x32_bf16(
      __builtin_bit_cast(bf16x8, a), __builtin_bit_cast(bf16x8, b), c, 0, 0, 0);
}

__device__ __forceinline__ uint2 tr16(u32 addr) {
  uint2 r;
  asm volatile("ds_read_b64_tr_b16 %0, %1" : "=v"(r) : "v"(addr));
  return r;
}

// ---------------------------------------------------------------------------
// Q projection. 256 threads: t<128 mv (o = t&63, h2 = t>>6, wave-uniform h2),
// t>=128 scalar (o2 = t-128). 8 tokens per block, weights cached in regs.
// ---------------------------------------------------------------------------
__global__ __launch_bounds__(256) void k_proj_q(
    const float* __restrict__ mv, const float* __restrict__ sc,
    const float* __restrict__ w_mv, const float* __restrict__ w_s2mv,
    const float* __restrict__ w_mv2s, const float* __restrict__ w_s,
    u16* __restrict__ qf)
{
  __shared__ float lds[8*288];
  const int t = threadIdx.x;
  const int tok0 = blockIdx.x * 8;

  for (int idx = t; idx < 8*64; idx += 256) {
    const int tk = idx >> 6, j = idx & 63;
    *(float4*)&lds[tk*288 + j*4] = *(const float4*)&mv[(size_t)(tok0+tk)*256 + j*4];
  }
  if (t < 64) {
    const int tk = t >> 3, j = t & 7;
    *(float4*)&lds[tk*288 + 256 + j*4] = *(const float4*)&sc[(size_t)(tok0+tk)*32 + j*4];
  }

  if (t < 128) {
    const int o = t & 63, h2 = t >> 6;
    float wreg[3][16];
    #pragma unroll
    for (int j = 0; j < 3; ++j)
      #pragma unroll
      for (int i = 0; i < 16; ++i)
        wreg[j][i] = w_mv[(((h2*2 + j)*64) + o)*16 + i];
    float ws2[32];
    if (h2 == 0)
      #pragma unroll
      for (int j = 0; j < 32; ++j) ws2[j] = w_s2mv[o*32 + j];
    const int c = o >> 3, hh = o & 7;
    __syncthreads();
    for (int tk = 0; tk < 8; ++tk) {
      const float* L = &lds[tk*288];
      float acc[8] = {0,0,0,0,0,0,0,0};
      if (h2 == 0) {
        #pragma unroll
        for (int i = 0; i < 16; ++i) {
          const float w0 = wreg[0][i], w1 = wreg[1][i], w2 = wreg[2][i];
          const float* mr = &L[i*16];
          acc[0] += mr[0]*w0; acc[1] += mr[1]*w1; acc[2] += mr[2]*w1; acc[3] += mr[3]*w1;
          acc[4] += mr[4]*w1; acc[5] += mr[5]*w2; acc[6] += mr[6]*w2; acc[7] += mr[7]*w2;
        }
        float a0 = 0.f;
        #pragma unroll
        for (int j = 0; j < 32; ++j) a0 += L[256+j]*ws2[j];
        acc[0] += a0;
        // eta for x=0..7: {1,1,-1,-1,-1,-1,-1,-1}
        acc[0] *= ATT_SCALE; acc[1] *= ATT_SCALE;
        #pragma unroll
        for (int xx = 2; xx < 8; ++xx) acc[xx] *= -ATT_SCALE;
      } else {
        #pragma unroll
        for (int i = 0; i < 16; ++i) {
          const float w0 = wreg[0][i], w1 = wreg[1][i], w2 = wreg[2][i];
          const float* mr = &L[i*16 + 8];
          acc[0] += mr[0]*w0; acc[1] += mr[1]*w0; acc[2] += mr[2]*w0; acc[3] += mr[3]*w1;
          acc[4] += mr[4]*w1; acc[5] += mr[5]*w1; acc[6] += mr[6]*w1; acc[7] += mr[7]*w2;
        }
        // eta for x=8..15: {1,1,1,1,1,1,-1,-1}
        #pragma unroll
        for (int xx = 0; xx < 6; ++xx) acc[xx] *= ATT_SCALE;
        acc[6] *= -ATT_SCALE; acc[7] *= -ATT_SCALE;
      }
      const int n = tok0 + tk, b = n >> 11, nn = n & 2047;
      u16* row = qf + ((size_t)(b*8 + hh)*2048 + nn)*160;
      uint4 u; u.x = pack2(acc[0],acc[1]); u.y = pack2(acc[2],acc[3]);
      u.z = pack2(acc[4],acc[5]); u.w = pack2(acc[6],acc[7]);
      *(uint4*)(row + c*16 + h2*8) = u;
      if (h2 == 1 && o < 8) {
        *(uint4*)(row + 144) = uint4{0,0,0,0};
        *(uint4*)(row + 152) = uint4{0,0,0,0};
      }
    }
  } else {
    const int o2 = t - 128;
    float wsv[32], wm2[16];
    #pragma unroll
    for (int j = 0; j < 32; ++j) wsv[j] = w_s[o2*32 + j];
    #pragma unroll
    for (int i = 0; i < 16; ++i) wm2[i] = w_mv2s[o2*16 + i];
    const int cs = o2 >> 3, hh = o2 & 7;
    __syncthreads();
    for (int tk = 0; tk < 8; ++tk) {
      const float* L = &lds[tk*288];
      float a = 0.f;
      #pragma unroll
      for (int j = 0; j < 32; ++j) a += L[256+j]*wsv[j];
      #pragma unroll
      for (int i = 0; i < 16; ++i) a += L[i*16]*wm2[i];
      const int n = tok0 + tk, b = n >> 11, nn = n & 2047;
      qf[((size_t)(b*8 + hh)*2048 + nn)*160 + 128 + cs] = bf16of(a * ATT_SCALE);
    }
  }
}

// ---------------------------------------------------------------------------
// KV projection. 512 threads: t<256 mv (o = t&127, h2 = t>>7), t>=256 scalar.
// ---------------------------------------------------------------------------
__global__ __launch_bounds__(512) void k_proj_kv(
    const float* __restrict__ mv, const float* __restrict__ sc,
    const float* __restrict__ w_mv, const float* __restrict__ w_s2mv,
    const float* __restrict__ w_mv2s, const float* __restrict__ w_s,
    u16* __restrict__ kf, u16* __restrict__ vf)
{
  __shared__ float lds[8*288];
  const int t = threadIdx.x;
  const int tok0 = blockIdx.x * 8;

  for (int idx = t; idx < 8*64; idx += 512) {
    const int tk = idx >> 6, j = idx & 63;
    *(float4*)&lds[tk*288 + j*4] = *(const float4*)&mv[(size_t)(tok0+tk)*256 + j*4];
  }
  if (t < 64) {
    const int tk = t >> 3, j = t & 7;
    *(float4*)&lds[tk*288 + 256 + j*4] = *(const float4*)&sc[(size_t)(tok0+tk)*32 + j*4];
  }

  if (t < 256) {
    const int o = t & 127, h2 = t >> 7;
    float wreg[3][16];
    #pragma unroll
    for (int j = 0; j < 3; ++j)
      #pragma unroll
      for (int i = 0; i < 16; ++i)
        wreg[j][i] = w_mv[(((h2*2 + j)*128) + o)*16 + i];
    float ws2[32];
    if (h2 == 0)
      #pragma unroll
      for (int j = 0; j < 32; ++j) ws2[j] = w_s2mv[o*32 + j];
    const int isv = o >> 6, oo = o & 63;
    const int c = oo >> 3, hh = oo & 7;
    u16* base = isv ? vf : kf;
    __syncthreads();
    for (int tk = 0; tk < 8; ++tk) {
      const float* L = &lds[tk*288];
      float acc[8] = {0,0,0,0,0,0,0,0};
      if (h2 == 0) {
        #pragma unroll
        for (int i = 0; i < 16; ++i) {
          const float w0 = wreg[0][i], w1 = wreg[1][i], w2 = wreg[2][i];
          const float* mr = &L[i*16];
          acc[0] += mr[0]*w0; acc[1] += mr[1]*w1; acc[2] += mr[2]*w1; acc[3] += mr[3]*w1;
          acc[4] += mr[4]*w1; acc[5] += mr[5]*w2; acc[6] += mr[6]*w2; acc[7] += mr[7]*w2;
        }
        float a0 = 0.f;
        #pragma unroll
        for (int j = 0; j < 32; ++j) a0 += L[256+j]*ws2[j];
        acc[0] += a0;
      } else {
        #pragma unroll
        for (int i = 0; i < 16; ++i) {
          const float w0 = wreg[0][i], w1 = wreg[1][i], w2 = wreg[2][i];
          const float* mr = &L[i*16 + 8];
          acc[0] += mr[0]*w0; acc[1] += mr[1]*w0; acc[2] += mr[2]*w0; acc[3] += mr[3]*w1;
          acc[4] += mr[4]*w1; acc[5] += mr[5]*w1; acc[6] += mr[6]*w1; acc[7] += mr[7]*w2;
        }
      }
      const int n = tok0 + tk, b = n >> 11, nn = n & 2047;
      u16* row = base + ((size_t)(b*8 + hh)*2048 + nn)*160;
      uint4 u; u.x = pack2(acc[0],acc[1]); u.y = pack2(acc[2],acc[3]);
      u.z = pack2(acc[4],acc[5]); u.w = pack2(acc[6],acc[7]);
      *(uint4*)(row + c*16 + h2*8) = u;
      if (h2 == 1 && oo < 8) {
        *(uint4*)(row + 144) = uint4{0,0,0,0};
        *(uint4*)(row + 152) = uint4{0,0,0,0};
      }
    }
  } else {
    const int o2 = t - 256;
    float wsv[32], wm2[16];
    #pragma unroll
    for (int j = 0; j < 32; ++j) wsv[j] = w_s[o2*32 + j];
    #pragma unroll
    for (int i = 0; i < 16; ++i) wm2[i] = w_mv2s[o2*16 + i];
    const int isv = o2 >> 7, oo2 = o2 & 127;
    const int cs = oo2 >> 3, hh = oo2 & 7;
    u16* base = isv ? vf : kf;
    __syncthreads();
    for (int tk = 0; tk < 8; ++tk) {
      const float* L = &lds[tk*288];
      float a = 0.f;
      #pragma unroll
      for (int j = 0; j < 32; ++j) a += L[256+j]*wsv[j];
      #pragma unroll
      for (int i = 0; i < 16; ++i) a += L[i*16]*wm2[i];
      const int n = tok0 + tk, b = n >> 11, nn = n & 2047;
      base[((size_t)(b*8 + hh)*2048 + nn)*160 + 128 + cs] = bf16of(a);
    }
  }
}

// ---------------------------------------------------------------------------
// Flash attention, bf16 MFMA. Block = (bh, 64 q rows), 4 waves.
// Swapped QK^T (S^T = K*Q^T) keeps P lane-local. PV = O = P*V with V staged
// row-major in [kblk][dblk][16][16] bf16 subtiles (b128 writes) and B-frags
// read via ds_read_b64_tr_b16.
// tr16 semantics (derived from m156/m162): each lane fetches 8B at its OWN
// addr; HW permutes within 16-lane groups so lane l elem j = u16 slot (l&3)
// of the chunk supplied by group-lane g = 4j + (l>>2). Hence lane (qi,hi)
// addr = subtile + 128*hi + (qi>>2)*32 + (qi&3)*8 yields
// elem j = V[k=16*kblk+4*hi+j][d=16*ds+qi] -- same k-slot bijection as pb.
// LDS: Ks[64][168] (21504 B) + Vsub 4*10*16*16*2 (20480 B) = 41984 B.
// ---------------------------------------------------------------------------
__global__ __launch_bounds__(256, 3) void k_attn(
    const u16* __restrict__ qf, const u16* __restrict__ kf,
    const u16* __restrict__ vf, const float* __restrict__ hsc,
    float* __restrict__ ho)
{
  __shared__ __align__(16) char smem[41984];
  u16 (*Ks)[168] = reinterpret_cast<u16(*)[168]>(smem);
  constexpr u32 Voff = 21504;

  const int orig = blockIdx.x;
  const int bid = (orig & 7) * 128 + (orig >> 3);   // XCD-contiguous (1024%8==0)
  const int qt = bid & 31;
  const int bh = bid >> 5;
  const int h  = bh & 7;
  const int t  = threadIdx.x;
  const int w  = t >> 6;
  const int lane = t & 63;
  const int qi = lane & 15;
  const int hi = lane >> 4;

  const u16* kg = kf + (size_t)bh * 2048 * 160;
  const u16* vg = vf + (size_t)bh * 2048 * 160;
  const u16* qg = qf + ((size_t)bh * 2048 + qt*64 + w*16) * 160;

  // Q fragments (B-operand): lane holds Q[q=qi][dc*32 + hi*8 + 0..7]
  uint4 qfr[5];
  #pragma unroll
  for (int dc = 0; dc < 5; ++dc)
    qfr[dc] = *(const uint4*)(qg + (size_t)qi*160 + dc*32 + hi*8);

  f32x4 o[9];
  #pragma unroll
  for (int d = 0; d < 9; ++d) o[d] = f32x4{0.f,0.f,0.f,0.f};
  float m = -INFINITY, l = 0.f;

  const int srow = t >> 2, sc4 = t & 3;

  uint4 kreg[5], vreg[5];
  {
    const u16* ks0 = kg + (size_t)srow * 160;
    const u16* vs0 = vg + (size_t)srow * 160;
    #pragma unroll
    for (int i = 0; i < 5; ++i) {
      const int c = sc4 + 4*i;
      kreg[i] = *(const uint4*)(ks0 + c*8);
      vreg[i] = *(const uint4*)(vs0 + c*8);
    }
  }

  for (int kt = 0; kt < 32; ++kt) {
    __syncthreads();
    // ---- stage K row-major + V subtiled, all b128 writes ----
    #pragma unroll
    for (int i = 0; i < 5; ++i) {
      const int c = sc4 + 4*i;
      *(uint4*)&Ks[srow][c*8] = kreg[i];
      *(uint4*)(smem + Voff + (srow>>4)*5120 + (c>>1)*512 + (srow&15)*32 + (c&1)*16) = vreg[i];
    }
    __syncthreads();
    if (kt < 31) {   // prefetch next tile; latency hides under compute below
      const u16* ksrc = kg + ((size_t)((kt+1)*64 + srow)) * 160;
      const u16* vsrc = vg + ((size_t)((kt+1)*64 + srow)) * 160;
      #pragma unroll
      for (int i = 0; i < 5; ++i) {
        const int c = sc4 + 4*i;
        kreg[i] = *(const uint4*)(ksrc + c*8);
        vreg[i] = *(const uint4*)(vsrc + c*8);
      }
    }

    // ---- S^T = K * Q^T : lane holds S^T[k = 16ks + 4hi + r][q = qi] ----
    f32x4 st[4];
    #pragma unroll
    for (int ks = 0; ks < 4; ++ks) {
      st[ks] = f32x4{0.f,0.f,0.f,0.f};
      #pragma unroll
      for (int dc = 0; dc < 5; ++dc) {
        const uint4 kf4 = *(const uint4*)&Ks[ks*16 + qi][dc*32 + hi*8];
        st[ks] = mfma_bf16(kf4, qfr[dc], st[ks]);
      }
    }

    // ---- online softmax (per q = qi) with defer-max ----
    float pm = st[0][0];
    #pragma unroll
    for (int ks = 0; ks < 4; ++ks)
      #pragma unroll
      for (int r = 0; r < 4; ++r) pm = fmaxf(pm, st[ks][r]);
    pm = fmaxf(pm, __shfl_xor(pm, 16));
    pm = fmaxf(pm, __shfl_xor(pm, 32));
    if (!__all(pm - m <= 8.f)) {
      const float mn = fmaxf(m, pm);
      const float rs = __expf(m - mn);   // per q = qi
      m = mn;
      l *= rs;
      float rsr[4];
      #pragma unroll
      for (int r = 0; r < 4; ++r) rsr[r] = __shfl(rs, hi*4 + r);
      #pragma unroll
      for (int d = 0; d < 9; ++d)
        #pragma unroll
        for (int r = 0; r < 4; ++r) o[d][r] *= rsr[r];  // O rows are q = 4hi+r
    }
    float ts = 0.f;
    #pragma unroll
    for (int ks = 0; ks < 4; ++ks)
      #pragma unroll
      for (int r = 0; r < 4; ++r) {
        const float p = __expf(st[ks][r] - m);
        st[ks][r] = p;
        ts += p;
      }
    ts += __shfl_xor(ts, 16);
    ts += __shfl_xor(ts, 32);
    l += ts;

    // ---- P -> bf16 A-frags (lane-local; slots: k = 32s+4hi+j / 32s+16+4hi+(j-4)) ----
    uint4 pb[2];
    #pragma unroll
    for (int s = 0; s < 2; ++s) {
      pb[s].x = pack2(st[2*s][0],   st[2*s][1]);
      pb[s].y = pack2(st[2*s][2],   st[2*s][3]);
      pb[s].z = pack2(st[2*s+1][0], st[2*s+1][1]);
      pb[s].w = pack2(st[2*s+1][2], st[2*s+1][3]);
    }

    // ---- O += P * V : B-frags via hw transpose reads (corrected addressing) ----
    const u32 vtb = Voff + (u32)(hi*128 + (qi>>2)*32 + (qi&3)*8);
    #pragma unroll
    for (int ds = 0; ds < 9; ++ds) {
      const u32 a0 = vtb + ds*512;
      uint2 t00 = tr16(a0);            // kblk 0: elem j = V[4hi+j][16ds+qi]
      uint2 t01 = tr16(a0 + 5120);     // kblk 1: k = 16+4hi+j
      uint2 t10 = tr16(a0 + 10240);    // kblk 2
      uint2 t11 = tr16(a0 + 15360);    // kblk 3
      asm volatile("s_waitcnt lgkmcnt(0)" ::: "memory");
      __builtin_amdgcn_sched_barrier(0);
      o[ds] = mfma_bf16(pb[0], uint4{t00.x, t00.y, t01.x, t01.y}, o[ds]);
      o[ds] = mfma_bf16(pb[1], uint4{t10.x, t10.y, t11.x, t11.y}, o[ds]);
    }
  }

  // ---- epilogue: lane holds O[q = w*16 + 4hi + r][d = 16ds + qi] ----
  __syncthreads();
  const float inv = hsc[h] / l;        // per q = qi
  float invr[4];
  #pragma unroll
  for (int r = 0; r < 4; ++r) invr[r] = __shfl(inv, hi*4 + r);
  float (*Ol)[148] = reinterpret_cast<float(*)[148]>(smem);  // 64*148*4 = 37888 B
  #pragma unroll
  for (int ds = 0; ds < 9; ++ds)
    #pragma unroll
    for (int r = 0; r < 4; ++r) {
      const int q = w*16 + hi*4 + r;
      const int loc = (ds < 8) ? (qi*8 + ds) : (128 + qi);   // col order x*8+c | 128+cs
      Ol[q][loc] = o[ds][r] * invr[r];
    }
  __syncthreads();
  // contiguous per-head store: ho (b,h,n,144)
  const size_t obase = ((size_t)bh*2048 + qt*64) * 144;
  for (int idx = t; idx < 64*36; idx += 256) {
    const int q = idx / 36, u = idx - q*36;
    *(float4*)(ho + obase + (size_t)q*144 + u*4) = *(const float4*)&Ol[q][u*4];
  }
}

// ---------------------------------------------------------------------------
// Output projection. 256 threads, 8 tokens/block, weights in regs.
// LDS fill gathers 8 heads from ho(b,h,n,144) into per-token component-major
// layout: slot x*64 + h*8 + c (mv), 1024 + h*16 + cs (scalar).
// ---------------------------------------------------------------------------
__global__ __launch_bounds__(256) void k_out(
    const float* __restrict__ ho,
    const float* __restrict__ w_mv, const float* __restrict__ w_s2mv,
    const float* __restrict__ w_mv2s, const float* __restrict__ w_s,
    float* __restrict__ out)
{
  constexpr int kGx[16] = {0,1,1,1,1,2,2,2,2,2,2,3,3,3,3,4};
  __shared__ float lh[8*1152];
  __shared__ float ob[256];
  __shared__ float csl[16];
  const int t = threadIdx.x;
  const int tok0 = blockIdx.x * 8;
  const int b0 = tok0 >> 11, n0 = tok0 & 2047;

  const int x = t >> 4, oB = t & 15;
  float4 wB[16];
  #pragma unroll
  for (int q = 0; q < 16; ++q)
    wB[q] = *(const float4*)&w_mv[(kGx[x]*16 + oB)*64 + q*4];

  float wC[16];
  float wD1[32], wD2[16];
  int oC = 0, pC = 0, oD = 0, pD = 0;
  if (t < 128) {
    oC = t >> 3; pC = t & 7;
    #pragma unroll
    for (int j = 0; j < 16; ++j) wC[j] = w_s2mv[oC*128 + pC*16 + j];
  } else {
    const int tt = t - 128;
    oD = tt >> 2; pD = tt & 3;
    #pragma unroll
    for (int j = 0; j < 32; ++j) wD1[j] = w_s[oD*128 + pD*32 + j];
    #pragma unroll
    for (int j = 0; j < 16; ++j) wD2[j] = w_mv2s[oD*64 + pD*16 + j];
  }

  // gather-fill: 8 tk x 8 heads x 36 float4
  for (int idx = t; idx < 2304; idx += 256) {
    const int tk = idx / 288, rem = idx - tk*288;
    const int hh = rem / 36, u = rem - hh*36;
    const float4 v = *(const float4*)&ho[(((size_t)(b0*8 + hh)*2048) + n0 + tk)*144 + u*4];
    int dst;
    if (u < 32) dst = (u>>1)*64 + hh*8 + (u&1)*4;
    else        dst = 1024 + hh*16 + (u-32)*4;
    *(float4*)&lh[tk*1152 + dst] = v;
  }
  __syncthreads();

  for (int tk = 0; tk < 8; ++tk) {
    const float* hp = &lh[tk*1152];
    // B: mv outputs
    float acc = 0.f;
    #pragma unroll
    for (int q = 0; q < 16; ++q) {
      const float4 hv = *(const float4*)&hp[x*64 + q*4];
      acc += hv.x*wB[q].x + hv.y*wB[q].y + hv.z*wB[q].z + hv.w*wB[q].w;
    }
    ob[t] = acc;
    if (t < 128) {
      // C: scalars -> grade-0
      float a = 0.f;
      #pragma unroll
      for (int j = 0; j < 16; ++j) a += hp[1024 + pC*16 + j]*wC[j];
      a += __shfl_xor(a, 1); a += __shfl_xor(a, 2); a += __shfl_xor(a, 4);
      if (pC == 0) csl[oC] = a;
    } else {
      // D: scalar outputs
      float a = 0.f;
      #pragma unroll
      for (int j = 0; j < 32; ++j) a += hp[1024 + pD*32 + j]*wD1[j];
      #pragma unroll
      for (int j = 0; j < 16; ++j) a += hp[pD*16 + j]*wD2[j];
      a += __shfl_xor(a, 1); a += __shfl_xor(a, 2);
      if (pD == 0) out[2097152 + (size_t)(tok0 + tk)*32 + oD] = a;
    }
    __syncthreads();
    // E: coalesced mv store; out idx = o*16 + xx with o=t>>4, xx=t&15
    float v = ob[(t & 15)*16 + (t >> 4)];
    if ((t & 15) == 0) v += csl[t >> 4];
    out[(size_t)(tok0 + tk)*256 + t] = v;
    __syncthreads();
  }
}

// ---------------------------------------------------------------------------
extern "C" void kernel_launch(void* const* d_in, const int* in_sizes, int n_in,
                              void* d_out, int out_size, void* d_ws, size_t ws_size,
                              hipStream_t stream) {
  const float* mv_kv    = (const float*)d_in[0];
  const float* mv_q     = (const float*)d_in[1];
  const float* s_kv     = (const float*)d_in[2];
  const float* s_q      = (const float*)d_in[3];
  const float* w_mv_q   = (const float*)d_in[4];
  const float* w_s2mv_q = (const float*)d_in[5];
  const float* w_mv2s_q = (const float*)d_in[6];
  const float* w_s_q    = (const float*)d_in[7];
  const float* w_mv_kv   = (const float*)d_in[8];
  const float* w_s2mv_kv = (const float*)d_in[9];
  const float* w_mv2s_kv = (const float*)d_in[10];
  const float* w_s_kv    = (const float*)d_in[11];
  const float* w_mv_o   = (const float*)d_in[12];
  const float* w_s2mv_o = (const float*)d_in[13];
  const float* w_mv2s_o = (const float*)d_in[14];
  const float* w_s_o    = (const float*)d_in[15];
  const float* hscale   = (const float*)d_in[16];

  u16* qf = (u16*)d_ws;
  u16* kf = qf + 10485760;
  u16* vf = kf + 10485760;
  float* ho = (float*)(vf + 10485760);

  k_proj_q <<<1024, 256, 0, stream>>>(mv_q,  s_q,  w_mv_q,  w_s2mv_q,  w_mv2s_q,  w_s_q,  qf);
  k_proj_kv<<<1024, 512, 0, stream>>>(mv_kv, s_kv, w_mv_kv, w_s2mv_kv, w_mv2s_kv, w_s_kv, kf, vf);
  k_attn   <<<1024, 256, 0, stream>>>(qf, kf, vf, hscale, ho);
  k_out    <<<1024, 256, 0, stream>>>(ho, w_mv_o, w_s2mv_o, w_mv2s_o, w_s_o, (float*)d_out);
}

// Round 7
// 297.186 us; speedup vs baseline: 2.1494x; 2.1494x over previous
//
#include <hip/hip_runtime.h>
#include <math.h>

// B=4, N=2048, H=8, CM=8, CS=16 ; head dim 144 padded to 160 (5 chunks of 32)
// qf/kf/vf: bf16 (b,h,n,160); ho: f32 (b,h,n,144) head-contiguous

typedef float f32x4 __attribute__((ext_vector_type(4)));
typedef __bf16 bf16x8 __attribute__((ext_vector_type(8)));
typedef unsigned short u16;
typedef unsigned int u32;

#define ATT_SCALE (1.0f/12.0f)

__device__ __forceinline__ u32 pack2(float a, float b) {
  u32 ua = __builtin_bit_cast(u32, a);
  u32 ub = __builtin_bit_cast(u32, b);
  ua = (ua + 0x7fffu + ((ua >> 16) & 1u)) >> 16;
  ub = (ub + 0x7fffu + ((ub >> 16) & 1u)) >> 16;
  return ua | (ub << 16);
}
__device__ __forceinline__ u16 bf16of(float a) { return (u16)(pack2(a, 0.f) & 0xffffu); }

__device__ __forceinline__ f32x4 mfma_bf16(uint4 a, uint4 b, f32x4 c) {
  return __builtin_amdgcn_mfma_f32_16x16x32_bf16(
      __builtin_bit_cast(bf16x8, a), __builtin_bit_cast(bf16x8, b), c, 0, 0, 0);
}

__device__ __forceinline__ uint2 tr16(u32 addr) {
  uint2 r;
  asm volatile("ds_read_b64_tr_b16 %0, %1" : "=v"(r) : "v"(addr));
  return r;
}

__device__ __forceinline__ void glds16(const void* g, void* l) {
  __builtin_amdgcn_global_load_lds((const __attribute__((address_space(1))) void*)g,
                                   (__attribute__((address_space(3))) void*)l, 16, 0, 0);
}

// ---------------------------------------------------------------------------
// Q projection. 256 threads: t<128 mv (o = t&63, h2 = t>>6, wave-uniform h2),
// t>=128 scalar (o2 = t-128). 8 tokens per block, weights cached in regs.
// ---------------------------------------------------------------------------
__global__ __launch_bounds__(256) void k_proj_q(
    const float* __restrict__ mv, const float* __restrict__ sc,
    const float* __restrict__ w_mv, const float* __restrict__ w_s2mv,
    const float* __restrict__ w_mv2s, const float* __restrict__ w_s,
    u16* __restrict__ qf)
{
  __shared__ float lds[8*288];
  const int t = threadIdx.x;
  const int tok0 = blockIdx.x * 8;

  for (int idx = t; idx < 8*64; idx += 256) {
    const int tk = idx >> 6, j = idx & 63;
    *(float4*)&lds[tk*288 + j*4] = *(const float4*)&mv[(size_t)(tok0+tk)*256 + j*4];
  }
  if (t < 64) {
    const int tk = t >> 3, j = t & 7;
    *(float4*)&lds[tk*288 + 256 + j*4] = *(const float4*)&sc[(size_t)(tok0+tk)*32 + j*4];
  }

  if (t < 128) {
    const int o = t & 63, h2 = t >> 6;
    float wreg[3][16];
    #pragma unroll
    for (int j = 0; j < 3; ++j)
      #pragma unroll
      for (int i = 0; i < 16; ++i)
        wreg[j][i] = w_mv[(((h2*2 + j)*64) + o)*16 + i];
    float ws2[32];
    if (h2 == 0)
      #pragma unroll
      for (int j = 0; j < 32; ++j) ws2[j] = w_s2mv[o*32 + j];
    const int c = o >> 3, hh = o & 7;
    __syncthreads();
    for (int tk = 0; tk < 8; ++tk) {
      const float* L = &lds[tk*288];
      float acc[8] = {0,0,0,0,0,0,0,0};
      if (h2 == 0) {
        #pragma unroll
        for (int i = 0; i < 16; ++i) {
          const float w0 = wreg[0][i], w1 = wreg[1][i], w2 = wreg[2][i];
          const float* mr = &L[i*16];
          acc[0] += mr[0]*w0; acc[1] += mr[1]*w1; acc[2] += mr[2]*w1; acc[3] += mr[3]*w1;
          acc[4] += mr[4]*w1; acc[5] += mr[5]*w2; acc[6] += mr[6]*w2; acc[7] += mr[7]*w2;
        }
        float a0 = 0.f;
        #pragma unroll
        for (int j = 0; j < 32; ++j) a0 += L[256+j]*ws2[j];
        acc[0] += a0;
        acc[0] *= ATT_SCALE; acc[1] *= ATT_SCALE;
        #pragma unroll
        for (int xx = 2; xx < 8; ++xx) acc[xx] *= -ATT_SCALE;
      } else {
        #pragma unroll
        for (int i = 0; i < 16; ++i) {
          const float w0 = wreg[0][i], w1 = wreg[1][i], w2 = wreg[2][i];
          const float* mr = &L[i*16 + 8];
          acc[0] += mr[0]*w0; acc[1] += mr[1]*w0; acc[2] += mr[2]*w0; acc[3] += mr[3]*w1;
          acc[4] += mr[4]*w1; acc[5] += mr[5]*w1; acc[6] += mr[6]*w1; acc[7] += mr[7]*w2;
        }
        #pragma unroll
        for (int xx = 0; xx < 6; ++xx) acc[xx] *= ATT_SCALE;
        acc[6] *= -ATT_SCALE; acc[7] *= -ATT_SCALE;
      }
      const int n = tok0 + tk, b = n >> 11, nn = n & 2047;
      u16* row = qf + ((size_t)(b*8 + hh)*2048 + nn)*160;
      uint4 u; u.x = pack2(acc[0],acc[1]); u.y = pack2(acc[2],acc[3]);
      u.z = pack2(acc[4],acc[5]); u.w = pack2(acc[6],acc[7]);
      *(uint4*)(row + c*16 + h2*8) = u;
      if (h2 == 1 && o < 8) {
        *(uint4*)(row + 144) = uint4{0,0,0,0};
        *(uint4*)(row + 152) = uint4{0,0,0,0};
      }
    }
  } else {
    const int o2 = t - 128;
    float wsv[32], wm2[16];
    #pragma unroll
    for (int j = 0; j < 32; ++j) wsv[j] = w_s[o2*32 + j];
    #pragma unroll
    for (int i = 0; i < 16; ++i) wm2[i] = w_mv2s[o2*16 + i];
    const int cs = o2 >> 3, hh = o2 & 7;
    __syncthreads();
    for (int tk = 0; tk < 8; ++tk) {
      const float* L = &lds[tk*288];
      float a = 0.f;
      #pragma unroll
      for (int j = 0; j < 32; ++j) a += L[256+j]*wsv[j];
      #pragma unroll
      for (int i = 0; i < 16; ++i) a += L[i*16]*wm2[i];
      const int n = tok0 + tk, b = n >> 11, nn = n & 2047;
      qf[((size_t)(b*8 + hh)*2048 + nn)*160 + 128 + cs] = bf16of(a * ATT_SCALE);
    }
  }
}

// ---------------------------------------------------------------------------
// KV projection. 512 threads: t<256 mv (o = t&127, h2 = t>>7), t>=256 scalar.
// ---------------------------------------------------------------------------
__global__ __launch_bounds__(512) void k_proj_kv(
    const float* __restrict__ mv, const float* __restrict__ sc,
    const float* __restrict__ w_mv, const float* __restrict__ w_s2mv,
    const float* __restrict__ w_mv2s, const float* __restrict__ w_s,
    u16* __restrict__ kf, u16* __restrict__ vf)
{
  __shared__ float lds[8*288];
  const int t = threadIdx.x;
  const int tok0 = blockIdx.x * 8;

  for (int idx = t; idx < 8*64; idx += 512) {
    const int tk = idx >> 6, j = idx & 63;
    *(float4*)&lds[tk*288 + j*4] = *(const float4*)&mv[(size_t)(tok0+tk)*256 + j*4];
  }
  if (t < 64) {
    const int tk = t >> 3, j = t & 7;
    *(float4*)&lds[tk*288 + 256 + j*4] = *(const float4*)&sc[(size_t)(tok0+tk)*32 + j*4];
  }

  if (t < 256) {
    const int o = t & 127, h2 = t >> 7;
    float wreg[3][16];
    #pragma unroll
    for (int j = 0; j < 3; ++j)
      #pragma unroll
      for (int i = 0; i < 16; ++i)
        wreg[j][i] = w_mv[(((h2*2 + j)*128) + o)*16 + i];
    float ws2[32];
    if (h2 == 0)
      #pragma unroll
      for (int j = 0; j < 32; ++j) ws2[j] = w_s2mv[o*32 + j];
    const int isv = o >> 6, oo = o & 63;
    const int c = oo >> 3, hh = oo & 7;
    u16* base = isv ? vf : kf;
    __syncthreads();
    for (int tk = 0; tk < 8; ++tk) {
      const float* L = &lds[tk*288];
      float acc[8] = {0,0,0,0,0,0,0,0};
      if (h2 == 0) {
        #pragma unroll
        for (int i = 0; i < 16; ++i) {
          const float w0 = wreg[0][i], w1 = wreg[1][i], w2 = wreg[2][i];
          const float* mr = &L[i*16];
          acc[0] += mr[0]*w0; acc[1] += mr[1]*w1; acc[2] += mr[2]*w1; acc[3] += mr[3]*w1;
          acc[4] += mr[4]*w1; acc[5] += mr[5]*w2; acc[6] += mr[6]*w2; acc[7] += mr[7]*w2;
        }
        float a0 = 0.f;
        #pragma unroll
        for (int j = 0; j < 32; ++j) a0 += L[256+j]*ws2[j];
        acc[0] += a0;
      } else {
        #pragma unroll
        for (int i = 0; i < 16; ++i) {
          const float w0 = wreg[0][i], w1 = wreg[1][i], w2 = wreg[2][i];
          const float* mr = &L[i*16 + 8];
          acc[0] += mr[0]*w0; acc[1] += mr[1]*w0; acc[2] += mr[2]*w0; acc[3] += mr[3]*w1;
          acc[4] += mr[4]*w1; acc[5] += mr[5]*w1; acc[6] += mr[6]*w1; acc[7] += mr[7]*w2;
        }
      }
      const int n = tok0 + tk, b = n >> 11, nn = n & 2047;
      u16* row = base + ((size_t)(b*8 + hh)*2048 + nn)*160;
      uint4 u; u.x = pack2(acc[0],acc[1]); u.y = pack2(acc[2],acc[3]);
      u.z = pack2(acc[4],acc[5]); u.w = pack2(acc[6],acc[7]);
      *(uint4*)(row + c*16 + h2*8) = u;
      if (h2 == 1 && oo < 8) {
        *(uint4*)(row + 144) = uint4{0,0,0,0};
        *(uint4*)(row + 152) = uint4{0,0,0,0};
      }
    }
  } else {
    const int o2 = t - 256;
    float wsv[32], wm2[16];
    #pragma unroll
    for (int j = 0; j < 32; ++j) wsv[j] = w_s[o2*32 + j];
    #pragma unroll
    for (int i = 0; i < 16; ++i) wm2[i] = w_mv2s[o2*16 + i];
    const int isv = o2 >> 7, oo2 = o2 & 127;
    const int cs = oo2 >> 3, hh = oo2 & 7;
    u16* base = isv ? vf : kf;
    __syncthreads();
    for (int tk = 0; tk < 8; ++tk) {
      const float* L = &lds[tk*288];
      float a = 0.f;
      #pragma unroll
      for (int j = 0; j < 32; ++j) a += L[256+j]*wsv[j];
      #pragma unroll
      for (int i = 0; i < 16; ++i) a += L[i*16]*wm2[i];
      const int n = tok0 + tk, b = n >> 11, nn = n & 2047;
      base[((size_t)(b*8 + hh)*2048 + nn)*160 + 128 + cs] = bf16of(a);
    }
  }
}

// ---------------------------------------------------------------------------
// Flash attention, bf16 MFMA. Block = (bh, 64 q rows), 4 waves. KVBLK=32,
// double-buffered LDS staged entirely via global_load_lds (no staging VGPRs):
//  - K tile 32x160 bf16 row-major, 10240 B, linear copy (stride 320 B reads
//    are conflict-free: 8 lanes/bank over the minimum 8 bank passes).
//  - V tile subtiled [2 kblk][10 dblk][16][16], DMA'd with per-lane permuted
//    global source addresses (16B chunks stay contiguous in global).
// 2-phase pipeline: STAGE(kt+1) -> compute(kt) -> __syncthreads() (compiler
// emits vmcnt(0) drain at the barrier). PV B-frags via ds_read_b64_tr_b16
// (R6-verified addressing). LDS: 2 x 20480 = 40960 B -> 3 blocks/CU.
// ---------------------------------------------------------------------------
__global__ __launch_bounds__(256, 3) void k_attn(
    const u16* __restrict__ qf, const u16* __restrict__ kf,
    const u16* __restrict__ vf, const float* __restrict__ hsc,
    float* __restrict__ ho)
{
  __shared__ __align__(16) char smem[40960];

  const int orig = blockIdx.x;
  const int bid = (orig & 7) * 128 + (orig >> 3);   // XCD-contiguous (1024%8==0)
  const int qt = bid & 31;
  const int bh = bid >> 5;
  const int h  = bh & 7;
  const int t  = threadIdx.x;
  const int w  = t >> 6;
  const int lane = t & 63;
  const int qi = lane & 15;
  const int hi = lane >> 4;

  const char* kgB = (const char*)(kf + (size_t)bh * 2048 * 160);
  const char* vgB = (const char*)(vf + (size_t)bh * 2048 * 160);
  const u16* qg = qf + ((size_t)bh * 2048 + qt*64 + w*16) * 160;

  // Q fragments (B-operand): lane holds Q[q=qi][dc*32 + hi*8 + 0..7]
  uint4 qfr[5];
  #pragma unroll
  for (int dc = 0; dc < 5; ++dc)
    qfr[dc] = *(const uint4*)(qg + (size_t)qi*160 + dc*32 + hi*8);

  f32x4 o[9];
  #pragma unroll
  for (int d = 0; d < 9; ++d) o[d] = f32x4{0.f,0.f,0.f,0.f};
  float m = -INFINITY, l = 0.f;

  // per-lane staging source offsets (within one 10240 B tile)
  int soff[5];
  if (w < 2) {
    #pragma unroll
    for (int j = 0; j < 5; ++j) soff[j] = w*5120 + j*1024 + lane*16;
  } else {
    #pragma unroll
    for (int j = 0; j < 5; ++j) {
      const int p = j*1024 + lane*16;
      const int dblk = p >> 9, krow = (p >> 5) & 15, dhalf = (p >> 4) & 1;
      soff[j] = ((w-2)*16 + krow)*320 + dblk*32 + dhalf*16;
    }
  }

  #define STAGE(KT, BUF) do {                                              \
    char* base_ = smem + (BUF)*20480;                                      \
    if (w < 2) {                                                           \
      const char* src_ = kgB + (size_t)(KT)*10240;                         \
      _Pragma("unroll")                                                    \
      for (int j = 0; j < 5; ++j)                                          \
        glds16(src_ + soff[j], base_ + w*5120 + j*1024);                   \
    } else {                                                               \
      const char* src_ = vgB + (size_t)(KT)*10240;                         \
      char* vb_ = base_ + 10240 + (w-2)*5120;                              \
      _Pragma("unroll")                                                    \
      for (int j = 0; j < 5; ++j)                                          \
        glds16(src_ + soff[j], vb_ + j*1024);                              \
    }                                                                      \
  } while (0)

  STAGE(0, 0);
  __syncthreads();   // vmcnt(0) drained by compiler before barrier

  for (int kt = 0; kt < 64; ++kt) {
    const int buf = kt & 1;
    if (kt < 63) STAGE(kt+1, buf^1);   // loads fly under compute below

    const char* KsB = smem + buf*20480;
    const u32 VoffB = (u32)(buf*20480 + 10240);

    // ---- S^T = K * Q^T : lane holds S^T[k = 16ks + 4hi + r][q = qi] ----
    f32x4 st[2];
    #pragma unroll
    for (int ks = 0; ks < 2; ++ks) {
      st[ks] = f32x4{0.f,0.f,0.f,0.f};
      #pragma unroll
      for (int dc = 0; dc < 5; ++dc) {
        const uint4 kf4 = *(const uint4*)(KsB + (ks*16 + qi)*320 + dc*64 + hi*16);
        st[ks] = mfma_bf16(kf4, qfr[dc], st[ks]);
      }
    }

    // ---- online softmax (per q = qi) with defer-max ----
    float pm = st[0][0];
    #pragma unroll
    for (int ks = 0; ks < 2; ++ks)
      #pragma unroll
      for (int r = 0; r < 4; ++r) pm = fmaxf(pm, st[ks][r]);
    pm = fmaxf(pm, __shfl_xor(pm, 16));
    pm = fmaxf(pm, __shfl_xor(pm, 32));
    if (!__all(pm - m <= 8.f)) {
      const float mn = fmaxf(m, pm);
      const float rs = __expf(m - mn);   // per q = qi
      m = mn;
      l *= rs;
      float rsr[4];
      #pragma unroll
      for (int r = 0; r < 4; ++r) rsr[r] = __shfl(rs, hi*4 + r);
      #pragma unroll
      for (int d = 0; d < 9; ++d)
        #pragma unroll
        for (int r = 0; r < 4; ++r) o[d][r] *= rsr[r];  // O rows are q = 4hi+r
    }
    float ts = 0.f;
    #pragma unroll
    for (int ks = 0; ks < 2; ++ks)
      #pragma unroll
      for (int r = 0; r < 4; ++r) {
        const float p = __expf(st[ks][r] - m);
        st[ks][r] = p;
        ts += p;
      }
    ts += __shfl_xor(ts, 16);
    ts += __shfl_xor(ts, 32);
    l += ts;

    // ---- P -> bf16 A-frag (slots: j<4 -> k=4hi+j ; j>=4 -> k=16+4hi+(j-4)) ----
    uint4 pb;
    pb.x = pack2(st[0][0], st[0][1]);
    pb.y = pack2(st[0][2], st[0][3]);
    pb.z = pack2(st[1][0], st[1][1]);
    pb.w = pack2(st[1][2], st[1][3]);

    // ---- O += P * V : B-frags via hw transpose reads (same k bijection) ----
    const u32 vtb = VoffB + (u32)(hi*128 + (qi>>2)*32 + (qi&3)*8);
    #pragma unroll
    for (int ds = 0; ds < 9; ++ds) {
      const u32 a0 = vtb + ds*512;
      uint2 t0 = tr16(a0);            // kblk 0: elem j = V[4hi+j][16ds+qi]
      uint2 t1 = tr16(a0 + 5120);     // kblk 1: k = 16+4hi+j
      asm volatile("s_waitcnt lgkmcnt(0)" ::: "memory");
      __builtin_amdgcn_sched_barrier(0);
      o[ds] = mfma_bf16(pb, uint4{t0.x, t0.y, t1.x, t1.y}, o[ds]);
    }

    __syncthreads();   // drains vmcnt(0): next tile staged; prev reads done
  }

  // ---- epilogue: lane holds O[q = w*16 + 4hi + r][d = 16ds + qi] ----
  const float inv = hsc[h] / l;        // per q = qi
  float invr[4];
  #pragma unroll
  for (int r = 0; r < 4; ++r) invr[r] = __shfl(inv, hi*4 + r);
  float (*Ol)[148] = reinterpret_cast<float(*)[148]>(smem);  // 37888 B <= 40960
  #pragma unroll
  for (int ds = 0; ds < 9; ++ds)
    #pragma unroll
    for (int r = 0; r < 4; ++r) {
      const int q = w*16 + hi*4 + r;
      const int loc = (ds < 8) ? (qi*8 + ds) : (128 + qi);
      Ol[q][loc] = o[ds][r] * invr[r];
    }
  __syncthreads();
  // contiguous per-head store: ho (b,h,n,144)
  const size_t obase = ((size_t)bh*2048 + qt*64) * 144;
  for (int idx = t; idx < 64*36; idx += 256) {
    const int q = idx / 36, u = idx - q*36;
    *(float4*)(ho + obase + (size_t)q*144 + u*4) = *(const float4*)&Ol[q][u*4];
  }
  #undef STAGE
}

// ---------------------------------------------------------------------------
// Output projection. 256 threads, 8 tokens/block, weights in regs.
// LDS fill gathers 8 heads from ho(b,h,n,144) into per-token component-major
// layout: slot x*64 + h*8 + c (mv), 1024 + h*16 + cs (scalar).
// ---------------------------------------------------------------------------
__global__ __launch_bounds__(256) void k_out(
    const float* __restrict__ ho,
    const float* __restrict__ w_mv, const float* __restrict__ w_s2mv,
    const float* __restrict__ w_mv2s, const float* __restrict__ w_s,
    float* __restrict__ out)
{
  constexpr int kGx[16] = {0,1,1,1,1,2,2,2,2,2,2,3,3,3,3,4};
  __shared__ float lh[8*1152];
  __shared__ float ob[256];
  __shared__ float csl[16];
  const int t = threadIdx.x;
  const int tok0 = blockIdx.x * 8;
  const int b0 = tok0 >> 11, n0 = tok0 & 2047;

  const int x = t >> 4, oB = t & 15;
  float4 wB[16];
  #pragma unroll
  for (int q = 0; q < 16; ++q)
    wB[q] = *(const float4*)&w_mv[(kGx[x]*16 + oB)*64 + q*4];

  float wC[16];
  float wD1[32], wD2[16];
  int oC = 0, pC = 0, oD = 0, pD = 0;
  if (t < 128) {
    oC = t >> 3; pC = t & 7;
    #pragma unroll
    for (int j = 0; j < 16; ++j) wC[j] = w_s2mv[oC*128 + pC*16 + j];
  } else {
    const int tt = t - 128;
    oD = tt >> 2; pD = tt & 3;
    #pragma unroll
    for (int j = 0; j < 32; ++j) wD1[j] = w_s[oD*128 + pD*32 + j];
    #pragma unroll
    for (int j = 0; j < 16; ++j) wD2[j] = w_mv2s[oD*64 + pD*16 + j];
  }

  // gather-fill: 8 tk x 8 heads x 36 float4
  for (int idx = t; idx < 2304; idx += 256) {
    const int tk = idx / 288, rem = idx - tk*288;
    const int hh = rem / 36, u = rem - hh*36;
    const float4 v = *(const float4*)&ho[(((size_t)(b0*8 + hh)*2048) + n0 + tk)*144 + u*4];
    int dst;
    if (u < 32) dst = (u>>1)*64 + hh*8 + (u&1)*4;
    else        dst = 1024 + hh*16 + (u-32)*4;
    *(float4*)&lh[tk*1152 + dst] = v;
  }
  __syncthreads();

  for (int tk = 0; tk < 8; ++tk) {
    const float* hp = &lh[tk*1152];
    // B: mv outputs
    float acc = 0.f;
    #pragma unroll
    for (int q = 0; q < 16; ++q) {
      const float4 hv = *(const float4*)&hp[x*64 + q*4];
      acc += hv.x*wB[q].x + hv.y*wB[q].y + hv.z*wB[q].z + hv.w*wB[q].w;
    }
    ob[t] = acc;
    if (t < 128) {
      // C: scalars -> grade-0
      float a = 0.f;
      #pragma unroll
      for (int j = 0; j < 16; ++j) a += hp[1024 + pC*16 + j]*wC[j];
      a += __shfl_xor(a, 1); a += __shfl_xor(a, 2); a += __shfl_xor(a, 4);
      if (pC == 0) csl[oC] = a;
    } else {
      // D: scalar outputs
      float a = 0.f;
      #pragma unroll
      for (int j = 0; j < 32; ++j) a += hp[1024 + pD*32 + j]*wD1[j];
      #pragma unroll
      for (int j = 0; j < 16; ++j) a += hp[pD*16 + j]*wD2[j];
      a += __shfl_xor(a, 1); a += __shfl_xor(a, 2);
      if (pD == 0) out[2097152 + (size_t)(tok0 + tk)*32 + oD] = a;
    }
    __syncthreads();
    // E: coalesced mv store; out idx = o*16 + xx with o=t>>4, xx=t&15
    float v = ob[(t & 15)*16 + (t >> 4)];
    if ((t & 15) == 0) v += csl[t >> 4];
    out[(size_t)(tok0 + tk)*256 + t] = v;
    __syncthreads();
  }
}

// ---------------------------------------------------------------------------
extern "C" void kernel_launch(void* const* d_in, const int* in_sizes, int n_in,
                              void* d_out, int out_size, void* d_ws, size_t ws_size,
                              hipStream_t stream) {
  const float* mv_kv    = (const float*)d_in[0];
  const float* mv_q     = (const float*)d_in[1];
  const float* s_kv     = (const float*)d_in[2];
  const float* s_q      = (const float*)d_in[3];
  const float* w_mv_q   = (const float*)d_in[4];
  const float* w_s2mv_q = (const float*)d_in[5];
  const float* w_mv2s_q = (const float*)d_in[6];
  const float* w_s_q    = (const float*)d_in[7];
  const float* w_mv_kv   = (const float*)d_in[8];
  const float* w_s2mv_kv = (const float*)d_in[9];
  const float* w_mv2s_kv = (const float*)d_in[10];
  const float* w_s_kv    = (const float*)d_in[11];
  const float* w_mv_o   = (const float*)d_in[12];
  const float* w_s2mv_o = (const float*)d_in[13];
  const float* w_mv2s_o = (const float*)d_in[14];
  const float* w_s_o    = (const float*)d_in[15];
  const float* hscale   = (const float*)d_in[16];

  u16* qf = (u16*)d_ws;
  u16* kf = qf + 10485760;
  u16* vf = kf + 10485760;
  float* ho = (float*)(vf + 10485760);

  k_proj_q <<<1024, 256, 0, stream>>>(mv_q,  s_q,  w_mv_q,  w_s2mv_q,  w_mv2s_q,  w_s_q,  qf);
  k_proj_kv<<<1024, 512, 0, stream>>>(mv_kv, s_kv, w_mv_kv, w_s2mv_kv, w_mv2s_kv, w_s_kv, kf, vf);
  k_attn   <<<1024, 256, 0, stream>>>(qf, kf, vf, hscale, ho);
  k_out    <<<1024, 256, 0, stream>>>(ho, w_mv_o, w_s2mv_o, w_mv2s_o, w_s_o, (float*)d_out);
}